// Round 1
// baseline (276.747 us; speedup 1.0000x reference)
//
#include <hip/hip_runtime.h>
#include <hip/hip_cooperative_groups.h>

namespace cg = cooperative_groups;

#define B_ 4
#define N_ 325
#define I_ 64
#define H_ 128
#define NODES (B_ * N_)
#define NZMAX 64                    // max nz/row ~35 (5% of 325 + self-loop)
#define NBLK (NODES / 4)            // 325 blocks, 4 nodes each

typedef unsigned short u16;
typedef unsigned int u32;

// f32 weight scratch, written each launch (converts + transposes).
__device__ __align__(16) float g_WT   [192 * 512];   // [k][g]  gates weights
__device__ __align__(16) float g_gcw  [128 * 128];   // [k][o]
__device__ __align__(16) float g_WsT  [128 * 128];   // [k][o]
__device__ __align__(16) float g_WtT  [128 * 128];   // [k][o]
__device__ __align__(16) float g_combT[256 * 128];   // [k][o]
__device__ float g_bias[512];                        // b_ih + b_hh
__device__ float g_svec[896];  // [0]=gc_b [128]=Ws_b [256]=Wt_b [384]=v [512]=ln_g [640]=ln_b [768]=comb_b

// activation scratch (cross-block only)
__device__ __align__(16) float g_support[(size_t)NODES * H_];
__device__ __align__(16) float g_h_graph[(size_t)NODES * H_];
__device__ __align__(16) float g_t_buf  [(size_t)NODES * H_];
// legacy-path-only scratch
__device__ __align__(16) float g_s_buf  [(size_t)NODES * H_];
__device__ __align__(16) float g_hl     [(size_t)NODES * H_];
__device__ u16 g_nz [(size_t)NODES * NZMAX];
__device__ int g_nzc[NODES];

__device__ __forceinline__ float bf2f(u16 u) { return __uint_as_float(((u32)u) << 16); }
__device__ __forceinline__ u16 f2bf(float f) {
    u32 u = __float_as_uint(f);
    u += 0x7fffu + ((u >> 16) & 1u);   // RNE
    return (u16)(u >> 16);
}
__device__ __forceinline__ float ldin(const void* p, size_t i, int f32) {
    return f32 ? ((const float*)p)[i] : bf2f(((const u16*)p)[i]);
}
__device__ __forceinline__ void stout(void* p, size_t i, float v, int f32) {
    if (f32) ((float*)p)[i] = v; else ((u16*)p)[i] = f2bf(v);
}
__device__ __forceinline__ float fast_rcp(float x) { return __builtin_amdgcn_rcpf(x); }
__device__ __forceinline__ float sigm(float x) { return fast_rcp(1.f + __expf(-x)); }
__device__ __forceinline__ float tanh_f(float x) {
    x = fminf(15.f, fmaxf(-15.f, x));
    float e = __expf(2.f * x);
    return (e - 1.f) * fast_rcp(e + 1.f);
}
// adj[0,0]==1.0 (self-loop): fp32 low16 = 0x0000, bf16 low16 = 0x3F80.
__device__ __forceinline__ int probe_f32(const void* adj) {
    return ((((const u32*)adj)[0] & 0xFFFFu) != 0x3F80u) ? 1 : 0;
}

#define PREP_TOT (98304 + 16384 * 3 + 32768 + 512 + 896)

__device__ __forceinline__ void prep_elem(int e, int f32,
    const void* W_ih, const void* W_hh, const void* b_ih, const void* b_hh,
    const void* gc_w, const void* gc_b, const void* Ws_w, const void* Ws_b,
    const void* Wt_w, const void* Wt_b, const void* vvec, const void* ln_g,
    const void* ln_b, const void* comb_w, const void* comb_b)
{
    int i = e;
    if (i < 98304) {                                   // WT[k][g]
        const int k = i >> 9, g = i & 511;
        g_WT[i] = (k < 64) ? ldin(W_ih, (size_t)g * 64 + k, f32)
                           : ldin(W_hh, (size_t)g * 128 + (k - 64), f32);
        return;
    }
    i -= 98304;
    if (i < 16384) { g_gcw[i] = ldin(gc_w, i, f32); return; }
    i -= 16384;
    if (i < 16384) {                                   // WsT[k][o]
        const int k = i >> 7, o = i & 127;
        g_WsT[i] = ldin(Ws_w, (size_t)o * 128 + k, f32);
        return;
    }
    i -= 16384;
    if (i < 16384) {
        const int k = i >> 7, o = i & 127;
        g_WtT[i] = ldin(Wt_w, (size_t)o * 128 + k, f32);
        return;
    }
    i -= 16384;
    if (i < 32768) {                                   // combT[k][o]
        const int k = i >> 7, o = i & 127;
        g_combT[i] = ldin(comb_w, (size_t)o * 256 + k, f32);
        return;
    }
    i -= 32768;
    if (i < 512) { g_bias[i] = ldin(b_ih, i, f32) + ldin(b_hh, i, f32); return; }
    i -= 512;
    {
        const int seg = i >> 7, k = i & 127;
        const void* src = (seg == 0) ? gc_b : (seg == 1) ? Ws_b : (seg == 2) ? Wt_b :
                          (seg == 3) ? vvec : (seg == 4) ? ln_g : (seg == 5) ? ln_b : comb_b;
        g_svec[i] = ldin(src, k, f32);
    }
}

// ===========================================================================
// Fused cooperative kernel: prep -> LSTM+support -> gather+proj -> attn+out.
// 3 grid.sync()s at the true cross-block dependency edges. Per-block state
// (nz lists, h_lstm, s-projection) never leaves LDS.
// ===========================================================================
__global__ __launch_bounds__(512, 4) void k_fused(
    const void* __restrict__ x, const void* __restrict__ adj,
    const void* __restrict__ h, const void* __restrict__ c,
    const void* __restrict__ W_ih, const void* __restrict__ W_hh,
    const void* __restrict__ b_ih, const void* __restrict__ b_hh,
    const void* __restrict__ gc_w, const void* __restrict__ gc_b,
    const void* __restrict__ Ws_w, const void* __restrict__ Ws_b,
    const void* __restrict__ Wt_w, const void* __restrict__ Wt_b,
    const void* __restrict__ vvec, const void* __restrict__ ln_g,
    const void* __restrict__ ln_b, const void* __restrict__ comb_w,
    const void* __restrict__ comb_b, void* __restrict__ out)
{
    cg::grid_group grid = cg::this_grid();
    const int f32 = probe_f32(adj);
    const int t = threadIdx.x;
    const int node0 = blockIdx.x * 4;
    const int lane = t & 63, w = t >> 6;

    __shared__ __align__(16) float4 xh4[192];    // [k] x {n0..n3}
    __shared__ __align__(16) float4 Gt4[512];    // [g] x {n0..n3}
    __shared__ __align__(16) float4 hl4[128];    // h_lstm, lives to combine
    __shared__ __align__(16) float4 hg4[128];    // h_graph
    __shared__ __align__(16) float4 att4[128];   // normalized attention
    __shared__ u16 nzi[4][NZMAX];
    __shared__ float nzv[4][NZMAX];
    __shared__ float nzs[4][NZMAX];
    __shared__ int cnt[4];
    __shared__ float s_i[4][H_];
    __shared__ float red[4][H_];
    __shared__ float part[4][4][H_];
    __shared__ float mu_[4], rstd_[4], smv[4];

    // ---- Phase 0: weight prep (grid-strided over all blocks) ----
    {
        const int tid = blockIdx.x * 512 + t;
        const int nth = gridDim.x * 512;
        for (int e = tid; e < PREP_TOT; e += nth)
            prep_elem(e, f32, W_ih, W_hh, b_ih, b_hh, gc_w, gc_b, Ws_w, Ws_b,
                      Wt_w, Wt_b, vvec, ln_g, ln_b, comb_w, comb_b);
    }
    grid.sync();

    // ---- Phase 1: gates -> cell -> support ----
    for (int e = t; e < 768; e += 512) {
        const int n = e / 192, k = e % 192;
        const int node = node0 + n;
        ((float*)&xh4[k])[n] = (k < 64) ? ldin(x, (size_t)node * 64 + k, f32)
                                        : ldin(h, (size_t)node * 128 + (k - 64), f32);
    }
    __syncthreads();
    {
        const int g = t;
        float a0 = 0.f, a1 = 0.f, a2 = 0.f, a3 = 0.f;
        #pragma unroll 8
        for (int k = 0; k < 192; ++k) {
            const float wv = g_WT[(size_t)k * 512 + g];
            const float4 xv = xh4[k];
            a0 = fmaf(xv.x, wv, a0); a1 = fmaf(xv.y, wv, a1);
            a2 = fmaf(xv.z, wv, a2); a3 = fmaf(xv.w, wv, a3);
        }
        const float bias = g_bias[g];
        Gt4[g] = make_float4(a0 + bias, a1 + bias, a2 + bias, a3 + bias);
    }
    __syncthreads();
    {
        const int n = t >> 7, hh = t & 127;
        const int node = node0 + n;
        float ig = ((const float*)&Gt4[hh])[n];
        float fg = ((const float*)&Gt4[128 + hh])[n];
        float gv = ((const float*)&Gt4[256 + hh])[n];
        float og = ((const float*)&Gt4[384 + hh])[n];
        float cl = sigm(fg) * ldin(c, (size_t)node * 128 + hh, f32) + sigm(ig) * tanh_f(gv);
        float hv = sigm(og) * tanh_f(cl);
        stout(out, (size_t)(NODES * H_) + (size_t)node * 128 + hh, cl, f32);
        ((float*)&hl4[hh])[n] = hv;
    }
    __syncthreads();
    {
        const int o = t & 127, n = t >> 7;     // n wave-uniform
        float acc = 0.f;
        #pragma unroll 8
        for (int k = 0; k < 128; ++k)
            acc = fmaf(((const float*)&hl4[k])[n], g_gcw[(size_t)k * 128 + o], acc);
        g_support[(size_t)(node0 + n) * 128 + o] = acc;
    }
    grid.sync();

    // ---- Phase 2: nz compaction + h_graph gather + s/t projections ----
    if (t < 4) cnt[t] = 0;
    __syncthreads();
    {
        const int n = t >> 7, jj = t & 127;    // 128 threads per adjacency row
        const size_t row = (size_t)(node0 + n) * N_;
        for (int j = jj; j < N_; j += 128) {
            float a = ldin(adj, row + j, f32);
            if (a != 0.f) {
                int p = atomicAdd(&cnt[n], 1);
                if (p < NZMAX) { nzi[n][p] = (u16)j; nzv[n][p] = a; }
            }
        }
    }
    __syncthreads();
    {
        const int n = t >> 7, o = t & 127;     // all 4 nodes in one pass
        const int node = node0 + n;
        const int bn = node / N_;
        const int cn = min(cnt[n], NZMAX);
        float acc = g_svec[o];                 // gc_b
        for (int p = 0; p < cn; ++p)
            acc = fmaf(nzv[n][p], g_support[((size_t)bn * N_ + nzi[n][p]) * 128 + o], acc);
        g_h_graph[(size_t)node * 128 + o] = acc;
        ((float*)&hg4[o])[n] = acc;
    }
    __syncthreads();
    {
        // 512 threads: which = s/t, half = K-half; partials reduced via LDS
        const int o = t & 127;
        const int which = (t >> 7) & 1;
        const int half  = t >> 8;
        const float* WT = which ? g_WtT : g_WsT;
        const int k0 = half * 64;
        float a0 = 0.f, a1 = 0.f, a2 = 0.f, a3 = 0.f;
        #pragma unroll 8
        for (int kk = 0; kk < 64; ++kk) {
            const int k = k0 + kk;
            const float wv = WT[(size_t)k * 128 + o];
            const float4 hv = hg4[k];
            a0 = fmaf(hv.x, wv, a0); a1 = fmaf(hv.y, wv, a1);
            a2 = fmaf(hv.z, wv, a2); a3 = fmaf(hv.w, wv, a3);
        }
        const int s = which * 2 + half;
        part[s][0][o] = a0; part[s][1][o] = a1;
        part[s][2][o] = a2; part[s][3][o] = a3;
    }
    __syncthreads();
    for (int e = t; e < 1024; e += 512) {
        const int which = e >> 9, n = (e >> 7) & 3, o = e & 127;
        const float vsum = part[which * 2][n][o] + part[which * 2 + 1][n][o]
                         + g_svec[128 + which * 128 + o];
        if (which) g_t_buf[(size_t)(node0 + n) * 128 + o] = vsum;
        else       s_i[n][o] = vsum;           // s stays in LDS (own node only)
    }
    grid.sync();

    // ---- Phase 3: scores + softmax + context + LN + combine ----
    {
        const int n = w & 3;                   // 2 waves per node, alternate p
        const int bn = (node0 + n) / N_;
        const int cn = min(cnt[n], NZMAX);
        const float v0 = g_svec[384 + lane], v1 = g_svec[384 + 64 + lane];
        const float si0 = s_i[n][lane], si1 = s_i[n][lane + 64];
        for (int p = (w >> 2); p < cn; p += 2) {
            const float* tj = g_t_buf + ((size_t)bn * N_ + nzi[n][p]) * 128;
            float a = v0 * tanh_f(si0 + tj[lane]) + v1 * tanh_f(si1 + tj[lane + 64]);
            #pragma unroll
            for (int off = 32; off > 0; off >>= 1) a += __shfl_xor(a, off);
            if (lane == 0) nzs[n][p] = a;
        }
    }
    __syncthreads();
    if (t < 4) {
        const int cn = min(cnt[t], NZMAX);
        float m = -1e30f;
        for (int p = 0; p < cn; ++p) m = fmaxf(m, nzs[t][p]);
        float ssum = 0.f;
        for (int p = 0; p < cn; ++p) { float e = __expf(nzs[t][p] - m); nzs[t][p] = e; ssum += e; }
        smv[t] = fast_rcp(ssum);
    }
    __syncthreads();
    {
        const int n = t >> 7, o = t & 127;     // all 4 nodes in one pass
        const int bn = (node0 + n) / N_;
        const int cn = min(cnt[n], NZMAX);
        float acc = 0.f;
        for (int p = 0; p < cn; ++p)
            acc = fmaf(nzs[n][p], g_h_graph[((size_t)bn * N_ + nzi[n][p]) * 128 + o], acc);
        red[n][o] = acc * smv[n];
    }
    __syncthreads();
    if (w < 4) {
        float x0 = red[w][lane], x1 = red[w][lane + 64];
        float sm = x0 + x1, sq = x0 * x0 + x1 * x1;
        #pragma unroll
        for (int off = 32; off > 0; off >>= 1) {
            sm += __shfl_xor(sm, off);
            sq += __shfl_xor(sq, off);
        }
        if (lane == 0) {
            float mu = sm * (1.f / H_);
            float var = fmaxf(sq * (1.f / H_) - mu * mu, 0.f);
            mu_[w] = mu;
            rstd_[w] = __builtin_amdgcn_rsqf(var + 1e-5f);
        }
    }
    __syncthreads();
    {
        const int n = t >> 7, k = t & 127;
        float xn = (red[n][k] - mu_[n]) * rstd_[n];
        ((float*)&att4[k])[n] = g_svec[512 + k] * xn + g_svec[640 + k];
    }
    __syncthreads();
    {
        // combine: quarter q covers K-slice [q*64, q*64+64); k<128 -> hl4
        const int o = t & 127, q = t >> 7;     // q wave-uniform
        const float4* src = (q < 2) ? hl4 : att4;
        const int kb = (q < 2) ? q * 64 : (q - 2) * 64;
        const int k0 = q * 64;
        float a0 = 0.f, a1 = 0.f, a2 = 0.f, a3 = 0.f;
        #pragma unroll 8
        for (int kk = 0; kk < 64; ++kk) {
            const float wv = g_combT[(size_t)(k0 + kk) * 128 + o];
            const float4 cv = src[kb + kk];
            a0 = fmaf(cv.x, wv, a0); a1 = fmaf(cv.y, wv, a1);
            a2 = fmaf(cv.z, wv, a2); a3 = fmaf(cv.w, wv, a3);
        }
        part[q][0][o] = a0; part[q][1][o] = a1;
        part[q][2][o] = a2; part[q][3][o] = a3;
    }
    __syncthreads();
    {
        const int n = t >> 7, k = t & 127;
        stout(out, (size_t)(node0 + n) * 128 + k,
              part[0][n][k] + part[1][n][k] + part[2][n][k] + part[3][n][k]
              + g_svec[768 + k], f32);
    }
}

// ===========================================================================
// Legacy 4-kernel fallback (proven path) in case cooperative launch is
// rejected by the runtime/capture. Verbatim from the previous version.
// ===========================================================================
__global__ __launch_bounds__(256) void k0_prep(
    const void* __restrict__ W_ih, const void* __restrict__ W_hh,
    const void* __restrict__ b_ih, const void* __restrict__ b_hh,
    const void* __restrict__ gc_w, const void* __restrict__ gc_b,
    const void* __restrict__ Ws_w, const void* __restrict__ Ws_b,
    const void* __restrict__ Wt_w, const void* __restrict__ Wt_b,
    const void* __restrict__ vvec, const void* __restrict__ ln_g,
    const void* __restrict__ ln_b, const void* __restrict__ comb_w,
    const void* __restrict__ comb_b, const void* __restrict__ adj)
{
    const int f32 = probe_f32(adj);
    const int tid = blockIdx.x * 256 + threadIdx.x;
    const int nth = gridDim.x * 256;
    for (int e = tid; e < PREP_TOT; e += nth)
        prep_elem(e, f32, W_ih, W_hh, b_ih, b_hh, gc_w, gc_b, Ws_w, Ws_b,
                  Wt_w, Wt_b, vvec, ln_g, ln_b, comb_w, comb_b);
}

__global__ __launch_bounds__(512) void k1_lstm(
    const void* __restrict__ x, const void* __restrict__ h, const void* __restrict__ c,
    const void* __restrict__ adj, void* __restrict__ out)
{
    const int f32 = probe_f32(adj);
    __shared__ __align__(16) float4 xh4[192];
    __shared__ __align__(16) float4 Gt4[512];
    __shared__ __align__(16) float4 hl4[128];
    const int node0 = blockIdx.x * 4;
    const int t = threadIdx.x;

    for (int e = t; e < 768; e += 512) {
        const int n = e / 192, k = e % 192;
        const int node = node0 + n;
        ((float*)&xh4[k])[n] = (k < 64) ? ldin(x, (size_t)node * 64 + k, f32)
                                        : ldin(h, (size_t)node * 128 + (k - 64), f32);
    }
    __syncthreads();
    {
        const int g = t;
        float a0 = 0.f, a1 = 0.f, a2 = 0.f, a3 = 0.f;
        #pragma unroll 8
        for (int k = 0; k < 192; ++k) {
            const float wv = g_WT[(size_t)k * 512 + g];
            const float4 xv = xh4[k];
            a0 = fmaf(xv.x, wv, a0); a1 = fmaf(xv.y, wv, a1);
            a2 = fmaf(xv.z, wv, a2); a3 = fmaf(xv.w, wv, a3);
        }
        const float bias = g_bias[g];
        Gt4[g] = make_float4(a0 + bias, a1 + bias, a2 + bias, a3 + bias);
    }
    __syncthreads();
    {
        const int n = t >> 7, hh = t & 127;
        const int node = node0 + n;
        float ig = ((const float*)&Gt4[hh])[n];
        float fg = ((const float*)&Gt4[128 + hh])[n];
        float gv = ((const float*)&Gt4[256 + hh])[n];
        float og = ((const float*)&Gt4[384 + hh])[n];
        float cl = sigm(fg) * ldin(c, (size_t)node * 128 + hh, f32) + sigm(ig) * tanh_f(gv);
        float hv = sigm(og) * tanh_f(cl);
        stout(out, (size_t)(NODES * H_) + (size_t)node * 128 + hh, cl, f32);
        g_hl[(size_t)node * 128 + hh] = hv;
        ((float*)&hl4[hh])[n] = hv;
    }
    __syncthreads();
    {
        const int o = t & 127, n = t >> 7;
        float acc = 0.f;
        #pragma unroll 8
        for (int k = 0; k < 128; ++k)
            acc = fmaf(((const float*)&hl4[k])[n], g_gcw[(size_t)k * 128 + o], acc);
        g_support[(size_t)(node0 + n) * 128 + o] = acc;
    }
}

__global__ __launch_bounds__(256) void k2_graph(const void* __restrict__ adj)
{
    const int f32 = probe_f32(adj);
    __shared__ __align__(16) float4 hg4[128];
    __shared__ u16 nzi[4][NZMAX];
    __shared__ float nzv[4][NZMAX];
    __shared__ int cnt[4];
    const int node0 = blockIdx.x * 4;
    const int t = threadIdx.x;
    const int lane = t & 63, w = t >> 6;

    if (t < 4) cnt[t] = 0;
    __syncthreads();
    for (int j = lane; j < N_; j += 64) {
        float a = ldin(adj, (size_t)(node0 + w) * N_ + j, f32);
        if (a != 0.f) {
            int p = atomicAdd(&cnt[w], 1);
            if (p < NZMAX) { nzi[w][p] = (u16)j; nzv[w][p] = a; }
        }
    }
    __syncthreads();
    if (t < 4) g_nzc[node0 + t] = min(cnt[t], NZMAX);
    #pragma unroll
    for (int n = 0; n < 4; ++n) {
        const int cnn = min(cnt[n], NZMAX);
        for (int p = t; p < cnn; p += 256) g_nz[(size_t)(node0 + n) * NZMAX + p] = nzi[n][p];
    }

    const int o = t & 127;
    const float gb = g_svec[o];
    #pragma unroll
    for (int ps = 0; ps < 2; ++ps) {
        const int n = (t >> 7) + 2 * ps;
        const int node = node0 + n;
        const int bn = node / N_;
        const int cnn = min(cnt[n], NZMAX);
        float acc = gb;
        for (int p = 0; p < cnn; ++p)
            acc = fmaf(nzv[n][p], g_support[((size_t)bn * N_ + nzi[n][p]) * 128 + o], acc);
        g_h_graph[(size_t)node * 128 + o] = acc;
        ((float*)&hg4[o])[n] = acc;
    }
    __syncthreads();
    {
        const int which = t >> 7;
        const float* WT = which ? g_WtT : g_WsT;
        const float bias = g_svec[128 + which * 128 + o];
        float a0 = 0.f, a1 = 0.f, a2 = 0.f, a3 = 0.f;
        #pragma unroll 8
        for (int k = 0; k < 128; ++k) {
            const float wv = WT[(size_t)k * 128 + o];
            const float4 hv = hg4[k];
            a0 = fmaf(hv.x, wv, a0); a1 = fmaf(hv.y, wv, a1);
            a2 = fmaf(hv.z, wv, a2); a3 = fmaf(hv.w, wv, a3);
        }
        float* dst = which ? g_t_buf : g_s_buf;
        dst[(size_t)(node0 + 0) * 128 + o] = a0 + bias;
        dst[(size_t)(node0 + 1) * 128 + o] = a1 + bias;
        dst[(size_t)(node0 + 2) * 128 + o] = a2 + bias;
        dst[(size_t)(node0 + 3) * 128 + o] = a3 + bias;
    }
}

__global__ __launch_bounds__(256) void k3_attn(
    const void* __restrict__ adj, void* __restrict__ out)
{
    const int f32 = probe_f32(adj);
    __shared__ __align__(16) float4 comb4[256];
    __shared__ float s_i[4][H_];
    __shared__ float red[4][H_];
    __shared__ float nzs[4][NZMAX];
    __shared__ u16 nzi[4][NZMAX];
    __shared__ float part[2][4][H_];
    __shared__ float mu_[4], rstd_[4], smv[4];
    __shared__ int cnt[4];
    const int node0 = blockIdx.x * 4;
    const int t = threadIdx.x;
    const int lane = t & 63, w = t >> 6;

    if (t < 4) cnt[t] = g_nzc[node0 + t];
    for (int e = t; e < 512; e += 256) {
        const int n = e >> 7, k = e & 127;
        const int node = node0 + n;
        s_i[n][k] = g_s_buf[(size_t)node * 128 + k];
        ((float*)&comb4[k])[n] = g_hl[(size_t)node * 128 + k];
    }
    __syncthreads();
    #pragma unroll
    for (int n = 0; n < 4; ++n)
        for (int p = t; p < cnt[n]; p += 256) nzi[n][p] = g_nz[(size_t)(node0 + n) * NZMAX + p];
    __syncthreads();

    {
        const int bn = (node0 + w) / N_;
        const int cn = cnt[w];
        const float v0 = g_svec[384 + lane], v1 = g_svec[384 + 64 + lane];
        const float si0 = s_i[w][lane], si1 = s_i[w][lane + 64];
        for (int p = 0; p < cn; ++p) {
            const float* tj = g_t_buf + ((size_t)bn * N_ + nzi[w][p]) * 128;
            float a = v0 * tanh_f(si0 + tj[lane]) + v1 * tanh_f(si1 + tj[lane + 64]);
            #pragma unroll
            for (int off = 32; off > 0; off >>= 1) a += __shfl_xor(a, off);
            if (lane == 0) nzs[w][p] = a;
        }
    }
    __syncthreads();
    if (t < 4) {
        const int cn = cnt[t];
        float m = -1e30f;
        for (int p = 0; p < cn; ++p) m = fmaxf(m, nzs[t][p]);
        float ssum = 0.f;
        for (int p = 0; p < cn; ++p) { float e = __expf(nzs[t][p] - m); nzs[t][p] = e; ssum += e; }
        smv[t] = fast_rcp(ssum);
    }
    __syncthreads();
    const int o = t & 127;
    #pragma unroll
    for (int ps = 0; ps < 2; ++ps) {
        const int n = (t >> 7) + 2 * ps;
        const int bn = (node0 + n) / N_;
        const int cn = cnt[n];
        float acc = 0.f;
        for (int p = 0; p < cn; ++p)
            acc = fmaf(nzs[n][p], g_h_graph[((size_t)bn * N_ + nzi[n][p]) * 128 + o], acc);
        red[n][o] = acc * smv[n];
    }
    __syncthreads();
    {
        float x0 = red[w][lane], x1 = red[w][lane + 64];
        float sm = x0 + x1, sq = x0 * x0 + x1 * x1;
        #pragma unroll
        for (int off = 32; off > 0; off >>= 1) {
            sm += __shfl_xor(sm, off);
            sq += __shfl_xor(sq, off);
        }
        if (lane == 0) {
            float mu = sm * (1.f / H_);
            float var = fmaxf(sq * (1.f / H_) - mu * mu, 0.f);
            mu_[w] = mu;
            rstd_[w] = __builtin_amdgcn_rsqf(var + 1e-5f);
        }
    }
    __syncthreads();
    for (int e = t; e < 512; e += 256) {
        const int n = e >> 7, k = e & 127;
        float xn = (red[n][k] - mu_[n]) * rstd_[n];
        ((float*)&comb4[128 + k])[n] = g_svec[512 + k] * xn + g_svec[640 + k];
    }
    __syncthreads();
    {
        const int half = t >> 7;
        float a0 = 0.f, a1 = 0.f, a2 = 0.f, a3 = 0.f;
        const int k0 = half * 128;
        #pragma unroll 8
        for (int kk = 0; kk < 128; ++kk) {
            const int k = k0 + kk;
            const float wv = g_combT[(size_t)k * 128 + o];
            const float4 cv = comb4[k];
            a0 = fmaf(cv.x, wv, a0); a1 = fmaf(cv.y, wv, a1);
            a2 = fmaf(cv.z, wv, a2); a3 = fmaf(cv.w, wv, a3);
        }
        part[half][0][o] = a0; part[half][1][o] = a1;
        part[half][2][o] = a2; part[half][3][o] = a3;
    }
    __syncthreads();
    for (int e = t; e < 512; e += 256) {
        const int n = e >> 7, k = e & 127;
        stout(out, (size_t)(node0 + n) * 128 + k,
              part[0][n][k] + part[1][n][k] + g_svec[768 + k], f32);
    }
}

// ---------------------------------------------------------------------------
extern "C" void kernel_launch(void* const* d_in, const int* in_sizes, int n_in,
                              void* d_out, int out_size, void* d_ws, size_t ws_size,
                              hipStream_t stream)
{
    (void)in_sizes; (void)n_in; (void)out_size; (void)d_ws; (void)ws_size;
    const void* x      = d_in[0];
    const void* adj    = d_in[1];
    const void* h      = d_in[2];
    const void* c      = d_in[3];
    const void* W_ih   = d_in[4];
    const void* W_hh   = d_in[5];
    const void* b_ih   = d_in[6];
    const void* b_hh   = d_in[7];
    const void* gc_w   = d_in[8];
    const void* gc_b   = d_in[9];
    const void* Ws_w   = d_in[10];
    const void* Ws_b   = d_in[11];
    const void* Wt_w   = d_in[12];
    const void* Wt_b   = d_in[13];
    const void* vvec   = d_in[14];
    const void* ln_g   = d_in[15];
    const void* ln_b   = d_in[16];
    const void* comb_w = d_in[17];
    const void* comb_b = d_in[18];

    void* args[] = {
        (void*)&x, (void*)&adj, (void*)&h, (void*)&c,
        (void*)&W_ih, (void*)&W_hh, (void*)&b_ih, (void*)&b_hh,
        (void*)&gc_w, (void*)&gc_b, (void*)&Ws_w, (void*)&Ws_b,
        (void*)&Wt_w, (void*)&Wt_b, (void*)&vvec, (void*)&ln_g,
        (void*)&ln_b, (void*)&comb_w, (void*)&comb_b, (void*)&d_out
    };
    hipError_t err = hipLaunchCooperativeKernel(
        reinterpret_cast<void*>(k_fused), dim3(NBLK), dim3(512),
        args, 0, stream);
    if (err != hipSuccess) {
        // Fallback: proven 4-kernel path.
        k0_prep <<<256, 256, 0, stream>>>(W_ih, W_hh, b_ih, b_hh, gc_w, gc_b,
                                          Ws_w, Ws_b, Wt_w, Wt_b, vvec, ln_g, ln_b,
                                          comb_w, comb_b, adj);
        k1_lstm <<<NBLK, 512, 0, stream>>>(x, h, c, adj, d_out);
        k2_graph<<<NBLK, 256, 0, stream>>>(adj);
        k3_attn <<<NBLK, 256, 0, stream>>>(adj, d_out);
    }
}